// Round 1
// baseline (80.736 us; speedup 1.0000x reference)
//
#include <hip/hip_runtime.h>
#include <hip/hip_fp16.h>
#include <stdint.h>

#define TOKENS 2048
#define DIM    2048
#define GROUP  128

typedef _Float16 half_t;
typedef __attribute__((ext_vector_type(2))) _Float16 f16x2;
typedef __attribute__((ext_vector_type(8))) _Float16 f16x8;
typedef __attribute__((ext_vector_type(4))) float    f32x4;

// ---------------- quantization ----------------

__device__ __forceinline__ float wave_sum(float v) {
#pragma unroll
  for (int off = 32; off > 0; off >>= 1)
    v += __shfl_xor(v, off, 64);
  return v;
}

// nearest point on MERGED_GRID with argmin-first tie-break (strict <, grid in
// concatenated order: sorted int part then sorted outlier part)
__device__ __forceinline__ float nearest_grid(float v) {
  const float G[29] = {
      -28.f, -24.f, -20.f, -16.f, -12.f, -8.f, -4.f, 0.f,
      4.f,   8.f,   12.f,  16.f,  20.f,  24.f, 28.f,
      -384.f, -256.f, -192.f, -128.f, -96.f, -64.f, -48.f,
      48.f,   64.f,   96.f,   128.f,  192.f, 256.f, 384.f};
  float best = G[0];
  float bd = fabsf(v - G[0]);
#pragma unroll
  for (int i = 1; i < 29; ++i) {
    float d = fabsf(v - G[i]);
    if (d < bd) { bd = d; best = G[i]; }
  }
  return best;
}

__global__ __launch_bounds__(256) void quant_kernel(
    const float* __restrict__ in, half_t* __restrict__ out, float alpha) {
  const int wid  = threadIdx.x >> 6;
  const int lane = threadIdx.x & 63;
  const int g    = blockIdx.x * 4 + wid;   // one wave per 128-elem group

  const size_t base = (size_t)g * GROUP + (size_t)lane * 2;
  const float2 xv = *reinterpret_cast<const float2*>(in + base);
  const float a = xv.x, b = xv.y;

  const float mean = wave_sum(a + b) * (1.0f / 128.0f);
  const float da = a - mean, db = b - mean;
  const float var = wave_sum(da * da + db * db) * (1.0f / 127.0f);
  const float stdv = sqrtf(var);
  // normal_max = max(|m+3s|,|m-3s|) = |m| + 3s
  const float scale = (fabsf(mean) + 3.0f * stdv) * alpha / 28.0f;

  float qa = nearest_grid(a / scale);
  float qb = nearest_grid(b / scale);
  // pair-local victim masking: even-pos outlier zeroes odd neighbor;
  // else odd-pos outlier zeroes even neighbor
  if (fabsf(qa) > 32.0f)      qb = 0.0f;
  else if (fabsf(qb) > 32.0f) qa = 0.0f;

  f16x2 hv;
  hv.x = (half_t)(qa * scale);   // RNE f32->f16, matches astype(float16)
  hv.y = (half_t)(qb * scale);
  *reinterpret_cast<f16x2*>(out + base) = hv;
}

// ---------------- GEMM: C[m,n] = sum_k A[m,k] * B[n,k] ----------------
// A = x_deq [2048][2048] f16 row-major, B = w_deq [2048][2048] f16 row-major
// BM=128, BN=64, BK=64; 256 threads = 4 waves (2x2), wave tile 64x32 (acc[4][2])

#define BM 128
#define BN 64
#define BK 64

__device__ __forceinline__ void gload_lds16(const half_t* g, half_t* l) {
  __builtin_amdgcn_global_load_lds(
      (__attribute__((address_space(1))) uint32_t*)g,
      (__attribute__((address_space(3))) uint32_t*)l, 16, 0, 0);
}

__global__ __launch_bounds__(256, 2) void gemm_kernel(
    const half_t* __restrict__ A, const half_t* __restrict__ B,
    float* __restrict__ C) {
  __shared__ half_t ldsA[2][BM * BK];  // 16 KB per buf
  __shared__ half_t ldsB[2][BN * BK];  // 8 KB per buf

  const int tid  = threadIdx.x;
  const int lane = tid & 63;
  const int wid  = tid >> 6;
  const int bm   = blockIdx.x & 15;   // 16 row-tiles
  const int bn   = blockIdx.x >> 4;   // 32 col-tiles
  const int wr   = wid >> 1;          // 0..1 (64 rows each)
  const int wc   = wid & 1;           // 0..1 (32 cols each)

  const half_t* gA = A + (size_t)(bm * BM) * DIM;
  const half_t* gB = B + (size_t)(bn * BN) * DIM;

  auto stage = [&](int buf, int kt) {
#pragma unroll
    for (int i = 0; i < 4; ++i) {
      int flat = (i * 256 + tid) * 8;   // element index in 128x64 tile
      int row = flat >> 6, col = flat & 63;
      gload_lds16(gA + (size_t)row * DIM + kt * BK + col, &ldsA[buf][flat]);
    }
#pragma unroll
    for (int i = 0; i < 2; ++i) {
      int flat = (i * 256 + tid) * 8;   // element index in 64x64 tile
      int row = flat >> 6, col = flat & 63;
      gload_lds16(gB + (size_t)row * DIM + kt * BK + col, &ldsB[buf][flat]);
    }
  };

  f32x4 acc[4][2] = {};

  stage(0, 0);
  __syncthreads();

  const int NT = DIM / BK;  // 32
  for (int kt = 0; kt < NT; ++kt) {
    const int cur = kt & 1;
    if (kt + 1 < NT) stage(cur ^ 1, kt + 1);

#pragma unroll
    for (int kk = 0; kk < 2; ++kk) {
      const int frow = lane & 15;
      const int fcol = kk * 32 + (lane >> 4) * 8;
      f16x8 af[4], bf[2];
#pragma unroll
      for (int m = 0; m < 4; ++m)
        af[m] = *reinterpret_cast<const f16x8*>(
            &ldsA[cur][(wr * 64 + m * 16 + frow) * BK + fcol]);
#pragma unroll
      for (int n = 0; n < 2; ++n)
        bf[n] = *reinterpret_cast<const f16x8*>(
            &ldsB[cur][(wc * 32 + n * 16 + frow) * BK + fcol]);
#pragma unroll
      for (int m = 0; m < 4; ++m)
#pragma unroll
        for (int n = 0; n < 2; ++n)
          acc[m][n] = __builtin_amdgcn_mfma_f32_16x16x32_f16(
              af[m], bf[n], acc[m][n], 0, 0, 0);
    }
    __syncthreads();  // drains vmcnt+lgkmcnt: next buf staged, reads done
  }

  // C/D layout: col = lane&15, row = (lane>>4)*4 + reg (dtype-independent)
  const int crow0 = bm * BM + wr * 64 + (lane >> 4) * 4;
  const int ccol0 = bn * BN + wc * 32 + (lane & 15);
#pragma unroll
  for (int m = 0; m < 4; ++m)
#pragma unroll
    for (int n = 0; n < 2; ++n)
#pragma unroll
      for (int r = 0; r < 4; ++r)
        C[(size_t)(crow0 + m * 16 + r) * DIM + (ccol0 + n * 16)] =
            acc[m][n][r];
}

// ---------------- launch ----------------

extern "C" void kernel_launch(void* const* d_in, const int* in_sizes, int n_in,
                              void* d_out, int out_size, void* d_ws,
                              size_t ws_size, hipStream_t stream) {
  const float* x = (const float*)d_in[0];
  const float* w = (const float*)d_in[1];
  float* out = (float*)d_out;

  half_t* xq = (half_t*)d_ws;                       // 8 MB
  half_t* wq = xq + (size_t)TOKENS * DIM;           // 8 MB

  const int ngroups = TOKENS * DIM / GROUP;         // 32768
  quant_kernel<<<ngroups / 4, 256, 0, stream>>>(x, xq, 0.9f);
  quant_kernel<<<ngroups / 4, 256, 0, stream>>>(w, wq, 1.0f);

  gemm_kernel<<<512, 256, 0, stream>>>(xq, wq, out);
}

// Round 2
// 49.730 us; speedup vs baseline: 1.6235x; 1.6235x over previous
//
#include <hip/hip_runtime.h>
#include <hip/hip_fp16.h>
#include <stdint.h>

#define TOKENS 2048
#define DIM    2048
#define GROUP  128

typedef _Float16 half_t;
typedef __attribute__((ext_vector_type(2))) _Float16 f16x2;
typedef __attribute__((ext_vector_type(8))) _Float16 f16x8;
typedef __attribute__((ext_vector_type(4))) float    f32x4;

// ---------------- quantization ----------------

__device__ __forceinline__ float wave_sum(float v) {
#pragma unroll
  for (int off = 32; off > 0; off >>= 1)
    v += __shfl_xor(v, off, 64);
  return v;
}

// nearest point on the merged grid, analytic form.
// int part: multiples of 4 in [-28,28]; outlier part: +-{48,64,96,128,192,256,384}.
// Ties (measure-zero on random data) resolved approximately; impact << threshold.
__device__ __forceinline__ float nearest_q(float u) {
  float qi = fminf(fmaxf(rintf(u * 0.25f) * 4.0f, -28.0f), 28.0f);
  float a = fabsf(u);
  float m = a <= 56.f  ? 48.f
          : a <= 80.f  ? 64.f
          : a <= 112.f ? 96.f
          : a <= 160.f ? 128.f
          : a <= 224.f ? 192.f
          : a <= 320.f ? 256.f : 384.f;
  float qo = copysignf(m, u);
  // tie between int and outlier candidate -> int grid wins (earlier in concat)
  return (fabsf(u - qo) < fabsf(u - qi)) ? qo : qi;
}

// both tensors in one launch: groups [0, 32768) = x (alpha 0.9),
// [32768, 65536) = w (alpha 1.0). out = xq ++ wq contiguous.
__global__ __launch_bounds__(256) void quant2_kernel(
    const float* __restrict__ x, const float* __restrict__ w,
    half_t* __restrict__ out) {
  const int wid  = threadIdx.x >> 6;
  const int lane = threadIdx.x & 63;
  const int g    = blockIdx.x * 4 + wid;         // global group id
  const int NG1  = TOKENS * DIM / GROUP;         // 32768

  const float alpha = (g < NG1) ? 0.9f : 1.0f;
  const float* src  = (g < NG1) ? x : w;
  const size_t sbase = (size_t)(g < NG1 ? g : g - NG1) * GROUP + lane * 2;

  const float2 xv = *reinterpret_cast<const float2*>(src + sbase);
  const float a = xv.x, b = xv.y;

  const float mean = wave_sum(a + b) * (1.0f / 128.0f);
  const float da = a - mean, db = b - mean;
  const float var = wave_sum(da * da + db * db) * (1.0f / 127.0f);
  const float stdv = sqrtf(var);
  const float scale = (fabsf(mean) + 3.0f * stdv) * alpha / 28.0f;
  const float rs = 1.0f / scale;

  float qa = nearest_q(a * rs);
  float qb = nearest_q(b * rs);
  // victim masking: even-pos outlier zeroes odd neighbor; else odd zeroes even
  if (fabsf(qa) > 32.0f)      qb = 0.0f;
  else if (fabsf(qb) > 32.0f) qa = 0.0f;

  f16x2 hv;
  hv.x = (half_t)(qa * scale);
  hv.y = (half_t)(qb * scale);
  *reinterpret_cast<f16x2*>(out + (size_t)g * GROUP + lane * 2) = hv;
}

// ---------------- GEMM: C[m,n] = sum_k A[m,k] * B[n,k] ----------------
// BM=128, BN=64, BK=64; 256 threads = 4 waves (2x2), wave tile 64x32.
// LDS rows are 128 B -> XOR-swizzle byte^=((row&7)<<4) applied on BOTH the
// global source address at staging time (LDS dest stays linear, as
// global_load_lds requires) and the ds_read address.

#define BM 128
#define BN 64
#define BK 64

__device__ __forceinline__ void gload_lds16(const half_t* g, half_t* l) {
  __builtin_amdgcn_global_load_lds(
      (__attribute__((address_space(1))) uint32_t*)g,
      (__attribute__((address_space(3))) uint32_t*)l, 16, 0, 0);
}

__global__ __launch_bounds__(256, 2) void gemm_kernel(
    const half_t* __restrict__ A, const half_t* __restrict__ B,
    float* __restrict__ C) {
  __shared__ half_t ldsA[2][BM * BK];  // 16 KB per buf
  __shared__ half_t ldsB[2][BN * BK];  // 8 KB per buf

  const int tid  = threadIdx.x;
  const int lane = tid & 63;
  const int wid  = tid >> 6;
  const int bm   = blockIdx.x & 15;   // 16 row-tiles
  const int bn   = blockIdx.x >> 4;   // 32 col-tiles
  const int wr   = wid >> 1;          // 0..1 (64 rows each)
  const int wc   = wid & 1;           // 0..1 (32 cols each)

  const half_t* gA = A + (size_t)(bm * BM) * DIM;
  const half_t* gB = B + (size_t)(bn * BN) * DIM;

  auto stage = [&](int buf, int kt) {
#pragma unroll
    for (int i = 0; i < 4; ++i) {
      int P   = (i * 256 + tid) * 16;            // physical byte in A tile
      int row = P >> 7;
      int cb  = (P & 127) ^ ((row & 7) << 4);    // logical col-byte (involution)
      gload_lds16(gA + (size_t)row * DIM + kt * BK + (cb >> 1),
                  (half_t*)((char*)&ldsA[buf][0] + P));
    }
#pragma unroll
    for (int i = 0; i < 2; ++i) {
      int P   = (i * 256 + tid) * 16;            // physical byte in B tile
      int row = P >> 7;
      int cb  = (P & 127) ^ ((row & 7) << 4);
      gload_lds16(gB + (size_t)row * DIM + kt * BK + (cb >> 1),
                  (half_t*)((char*)&ldsB[buf][0] + P));
    }
  };

  f32x4 acc[4][2] = {};

  stage(0, 0);
  __syncthreads();

  const int NT = DIM / BK;  // 32
  for (int kt = 0; kt < NT; ++kt) {
    const int cur = kt & 1;
    if (kt + 1 < NT) stage(cur ^ 1, kt + 1);

    const int frow = lane & 15;
    const int swz  = (frow & 7) << 4;
#pragma unroll
    for (int kk = 0; kk < 2; ++kk) {
      const int cb = kk * 64 + ((lane >> 4) << 4);  // logical col-byte
      const int pc = cb ^ swz;                      // physical col-byte
      f16x8 af[4], bf[2];
#pragma unroll
      for (int m = 0; m < 4; ++m) {
        int row = wr * 64 + m * 16 + frow;          // row&7 == frow&7
        af[m] = *reinterpret_cast<const f16x8*>(
            (const char*)&ldsA[cur][0] + (row << 7) + pc);
      }
#pragma unroll
      for (int n = 0; n < 2; ++n) {
        int row = wc * 32 + n * 16 + frow;          // row&7 == frow&7
        bf[n] = *reinterpret_cast<const f16x8*>(
            (const char*)&ldsB[cur][0] + (row << 7) + pc);
      }
#pragma unroll
      for (int m = 0; m < 4; ++m)
#pragma unroll
        for (int n = 0; n < 2; ++n)
          acc[m][n] = __builtin_amdgcn_mfma_f32_16x16x32_f16(
              af[m], bf[n], acc[m][n], 0, 0, 0);
    }
    __syncthreads();
  }

  // C/D layout: col = lane&15, row = (lane>>4)*4 + reg
  const int crow0 = bm * BM + wr * 64 + (lane >> 4) * 4;
  const int ccol0 = bn * BN + wc * 32 + (lane & 15);
#pragma unroll
  for (int m = 0; m < 4; ++m)
#pragma unroll
    for (int n = 0; n < 2; ++n)
#pragma unroll
      for (int r = 0; r < 4; ++r)
        C[(size_t)(crow0 + m * 16 + r) * DIM + (ccol0 + n * 16)] =
            acc[m][n][r];
}

// ---------------- launch ----------------

extern "C" void kernel_launch(void* const* d_in, const int* in_sizes, int n_in,
                              void* d_out, int out_size, void* d_ws,
                              size_t ws_size, hipStream_t stream) {
  const float* x = (const float*)d_in[0];
  const float* w = (const float*)d_in[1];
  float* out = (float*)d_out;

  half_t* xq = (half_t*)d_ws;                     // 8 MB (xq ++ wq)

  const int ngroups = 2 * TOKENS * DIM / GROUP;   // 65536
  quant2_kernel<<<ngroups / 4, 256, 0, stream>>>(x, w, xq);

  half_t* wq = xq + (size_t)TOKENS * DIM;
  gemm_kernel<<<512, 256, 0, stream>>>(xq, wq, out);
}

// Round 3
// 45.620 us; speedup vs baseline: 1.7697x; 1.0901x over previous
//
#include <hip/hip_runtime.h>
#include <hip/hip_fp16.h>
#include <stdint.h>

#define TOKENS 2048
#define DIM    2048
#define GROUP  128

typedef _Float16 half_t;
typedef __attribute__((ext_vector_type(2))) _Float16 f16x2;
typedef __attribute__((ext_vector_type(8))) _Float16 f16x8;
typedef __attribute__((ext_vector_type(4))) float    f32x4;

// ---------------- quantization ----------------

__device__ __forceinline__ float wave_sum(float v) {
#pragma unroll
  for (int off = 32; off > 0; off >>= 1)
    v += __shfl_xor(v, off, 64);
  return v;
}

// nearest point on the merged grid, analytic form.
__device__ __forceinline__ float nearest_q(float u) {
  float qi = fminf(fmaxf(rintf(u * 0.25f) * 4.0f, -28.0f), 28.0f);
  float a = fabsf(u);
  float m = a <= 56.f  ? 48.f
          : a <= 80.f  ? 64.f
          : a <= 112.f ? 96.f
          : a <= 160.f ? 128.f
          : a <= 224.f ? 192.f
          : a <= 320.f ? 256.f : 384.f;
  float qo = copysignf(m, u);
  return (fabsf(u - qo) < fabsf(u - qi)) ? qo : qi;
}

__global__ __launch_bounds__(256) void quant2_kernel(
    const float* __restrict__ x, const float* __restrict__ w,
    half_t* __restrict__ out) {
  const int wid  = threadIdx.x >> 6;
  const int lane = threadIdx.x & 63;
  const int g    = blockIdx.x * 4 + wid;
  const int NG1  = TOKENS * DIM / GROUP;   // 32768

  const float alpha = (g < NG1) ? 0.9f : 1.0f;
  const float* src  = (g < NG1) ? x : w;
  const size_t sbase = (size_t)(g < NG1 ? g : g - NG1) * GROUP + lane * 2;

  const float2 xv = *reinterpret_cast<const float2*>(src + sbase);
  const float a = xv.x, b = xv.y;

  const float mean = wave_sum(a + b) * (1.0f / 128.0f);
  const float da = a - mean, db = b - mean;
  const float var = wave_sum(da * da + db * db) * (1.0f / 127.0f);
  const float stdv = sqrtf(var);
  const float scale = (fabsf(mean) + 3.0f * stdv) * alpha / 28.0f;
  const float rs = 1.0f / scale;

  float qa = nearest_q(a * rs);
  float qb = nearest_q(b * rs);
  if (fabsf(qa) > 32.0f)      qb = 0.0f;
  else if (fabsf(qb) > 32.0f) qa = 0.0f;

  f16x2 hv;
  hv.x = (half_t)(qa * scale);
  hv.y = (half_t)(qb * scale);
  *reinterpret_cast<f16x2*>(out + (size_t)g * GROUP + lane * 2) = hv;
}

// ---------------- GEMM: C[m,n] = sum_k A[m,k] * B[n,k] ----------------
// BM=128, BN=64, BK=64; 256 threads = 4 waves (2x2), wave tile 64x32.
// 3-deep LDS pipeline with counted vmcnt (T4): stage(kt+2) issued each iter,
// s_waitcnt vmcnt(12) keeps kt+1/kt+2's 12 loads in flight across raw
// s_barrier. XOR swizzle byte^=((row&7)<<4) on both global source (LDS dest
// linear, per global_load_lds rules) and ds_read address.

#define BM 128
#define BN 64
#define BK 64

__device__ __forceinline__ void gload_lds16(const half_t* g, half_t* l) {
  __builtin_amdgcn_global_load_lds(
      (__attribute__((address_space(1))) uint32_t*)g,
      (__attribute__((address_space(3))) uint32_t*)l, 16, 0, 0);
}

__global__ __launch_bounds__(256, 2) void gemm_kernel(
    const half_t* __restrict__ A, const half_t* __restrict__ B,
    float* __restrict__ C) {
  __shared__ half_t ldsA[3][BM * BK];  // 3 x 16 KB
  __shared__ half_t ldsB[3][BN * BK];  // 3 x 8 KB   (72 KB total)

  const int tid  = threadIdx.x;
  const int lane = tid & 63;
  const int wid  = tid >> 6;
  const int bm   = blockIdx.x & 15;
  const int bn   = blockIdx.x >> 4;
  const int wr   = wid >> 1;
  const int wc   = wid & 1;

  const half_t* gA = A + (size_t)(bm * BM) * DIM;
  const half_t* gB = B + (size_t)(bn * BN) * DIM;

  auto stage = [&](half_t* dA, half_t* dB, int kt) {
#pragma unroll
    for (int i = 0; i < 4; ++i) {
      int P   = (i * 256 + tid) * 16;
      int row = P >> 7;
      int cb  = (P & 127) ^ ((row & 7) << 4);
      gload_lds16(gA + (size_t)row * DIM + kt * BK + (cb >> 1),
                  (half_t*)((char*)dA + P));
    }
#pragma unroll
    for (int i = 0; i < 2; ++i) {
      int P   = (i * 256 + tid) * 16;
      int row = P >> 7;
      int cb  = (P & 127) ^ ((row & 7) << 4);
      gload_lds16(gB + (size_t)row * DIM + kt * BK + (cb >> 1),
                  (half_t*)((char*)dB + P));
    }
  };

  f32x4 acc[4][2] = {};

  auto compute = [&](const half_t* cA, const half_t* cB) {
    const int frow = lane & 15;
    const int swz  = (frow & 7) << 4;
#pragma unroll
    for (int kk = 0; kk < 2; ++kk) {
      const int cb = kk * 64 + ((lane >> 4) << 4);
      const int pc = cb ^ swz;
      f16x8 af[4], bf[2];
#pragma unroll
      for (int m = 0; m < 4; ++m) {
        int row = wr * 64 + m * 16 + frow;
        af[m] = *reinterpret_cast<const f16x8*>(
            (const char*)cA + (row << 7) + pc);
      }
#pragma unroll
      for (int n = 0; n < 2; ++n) {
        int row = wc * 32 + n * 16 + frow;
        bf[n] = *reinterpret_cast<const f16x8*>(
            (const char*)cB + (row << 7) + pc);
      }
      __builtin_amdgcn_s_setprio(1);
#pragma unroll
      for (int m = 0; m < 4; ++m)
#pragma unroll
        for (int n = 0; n < 2; ++n)
          acc[m][n] = __builtin_amdgcn_mfma_f32_16x16x32_f16(
              af[m], bf[n], acc[m][n], 0, 0, 0);
      __builtin_amdgcn_s_setprio(0);
    }
  };

  half_t* A0 = &ldsA[0][0];  half_t* B0 = &ldsB[0][0];
  half_t* A1 = &ldsA[1][0];  half_t* B1 = &ldsB[1][0];
  half_t* A2 = &ldsA[2][0];  half_t* B2 = &ldsB[2][0];

  stage(A0, B0, 0);
  stage(A1, B1, 1);

  auto iter = [&](int kt, const half_t* cA, const half_t* cB,
                  half_t* sA, half_t* sB) {
    stage(sA, sB, kt + 2);
    asm volatile("s_waitcnt vmcnt(12)" ::: "memory");
    __builtin_amdgcn_s_barrier();
    compute(cA, cB);
    __builtin_amdgcn_s_barrier();
  };

  for (int kt = 0; kt < 30; kt += 3) {   // NT=32, main 30 iters
    iter(kt + 0, A0, B0, A2, B2);
    iter(kt + 1, A1, B1, A0, B0);
    iter(kt + 2, A2, B2, A1, B1);
  }
  // kt = 30: only loads for 30,31 outstanding
  asm volatile("s_waitcnt vmcnt(6)" ::: "memory");
  __builtin_amdgcn_s_barrier();
  compute(A0, B0);
  // kt = 31
  asm volatile("s_waitcnt vmcnt(0)" ::: "memory");
  __builtin_amdgcn_s_barrier();
  compute(A1, B1);

  const int crow0 = bm * BM + wr * 64 + (lane >> 4) * 4;
  const int ccol0 = bn * BN + wc * 32 + (lane & 15);
#pragma unroll
  for (int m = 0; m < 4; ++m)
#pragma unroll
    for (int n = 0; n < 2; ++n)
#pragma unroll
      for (int r = 0; r < 4; ++r)
        C[(size_t)(crow0 + m * 16 + r) * DIM + (ccol0 + n * 16)] =
            acc[m][n][r];
}

// ---------------- launch ----------------

extern "C" void kernel_launch(void* const* d_in, const int* in_sizes, int n_in,
                              void* d_out, int out_size, void* d_ws,
                              size_t ws_size, hipStream_t stream) {
  const float* x = (const float*)d_in[0];
  const float* w = (const float*)d_in[1];
  float* out = (float*)d_out;

  half_t* xq = (half_t*)d_ws;                     // xq ++ wq, 16 MB

  const int ngroups = 2 * TOKENS * DIM / GROUP;   // 65536
  quant2_kernel<<<ngroups / 4, 256, 0, stream>>>(x, w, xq);

  half_t* wq = xq + (size_t)TOKENS * DIM;
  gemm_kernel<<<512, 256, 0, stream>>>(xq, wq, out);
}

// Round 4
// 43.331 us; speedup vs baseline: 1.8632x; 1.0528x over previous
//
#include <hip/hip_runtime.h>
#include <hip/hip_fp16.h>
#include <stdint.h>

#define TOKENS 2048
#define DIM    2048
#define GROUP  128

typedef _Float16 half_t;
typedef __attribute__((ext_vector_type(4)))  _Float16 f16x4;
typedef __attribute__((ext_vector_type(8)))  _Float16 f16x8;
typedef __attribute__((ext_vector_type(16))) float    f32x16;

// ---------------- quantization ----------------
// float4 per lane: 32 lanes per 128-elem group, 2 groups per wave.

__device__ __forceinline__ float group32_sum(float v) {
#pragma unroll
  for (int off = 16; off > 0; off >>= 1)
    v += __shfl_xor(v, off, 64);   // offsets <32 keep 32-lane halves closed
  return v;
}

// nearest point on the merged grid, analytic form.
__device__ __forceinline__ float nearest_q(float u) {
  float qi = fminf(fmaxf(rintf(u * 0.25f) * 4.0f, -28.0f), 28.0f);
  float a = fabsf(u);
  float m = a <= 56.f  ? 48.f
          : a <= 80.f  ? 64.f
          : a <= 112.f ? 96.f
          : a <= 160.f ? 128.f
          : a <= 224.f ? 192.f
          : a <= 320.f ? 256.f : 384.f;
  float qo = copysignf(m, u);
  return (fabsf(u - qo) < fabsf(u - qi)) ? qo : qi;
}

__global__ __launch_bounds__(256) void quant2_kernel(
    const float* __restrict__ x, const float* __restrict__ w,
    half_t* __restrict__ out) {
  const int wid  = threadIdx.x >> 6;
  const int lane = threadIdx.x & 63;
  const int l    = lane & 31;
  const int g    = blockIdx.x * 8 + wid * 2 + (lane >> 5);
  const int NG1  = TOKENS * DIM / GROUP;   // 32768

  const float alpha = (g < NG1) ? 0.9f : 1.0f;
  const float* src  = (g < NG1) ? x : w;
  const size_t sbase = (size_t)(g < NG1 ? g : g - NG1) * GROUP + l * 4;

  const float4 v = *reinterpret_cast<const float4*>(src + sbase);

  const float mean = group32_sum(v.x + v.y + v.z + v.w) * (1.0f / 128.0f);
  const float d0 = v.x - mean, d1 = v.y - mean, d2 = v.z - mean, d3 = v.w - mean;
  const float var = group32_sum(d0 * d0 + d1 * d1 + d2 * d2 + d3 * d3) *
                    (1.0f / 127.0f);
  const float scale = (fabsf(mean) + 3.0f * sqrtf(var)) * alpha / 28.0f;
  const float rs = 1.0f / scale;

  float q0 = nearest_q(v.x * rs);
  float q1 = nearest_q(v.y * rs);
  float q2 = nearest_q(v.z * rs);
  float q3 = nearest_q(v.w * rs);
  // victim masking within lane-local pairs
  if (fabsf(q0) > 32.0f)      q1 = 0.0f;
  else if (fabsf(q1) > 32.0f) q0 = 0.0f;
  if (fabsf(q2) > 32.0f)      q3 = 0.0f;
  else if (fabsf(q3) > 32.0f) q2 = 0.0f;

  f16x4 hv;
  hv.x = (half_t)(q0 * scale);
  hv.y = (half_t)(q1 * scale);
  hv.z = (half_t)(q2 * scale);
  hv.w = (half_t)(q3 * scale);
  *reinterpret_cast<f16x4*>(out + (size_t)g * GROUP + l * 4) = hv;
}

// ---------------- GEMM: C[m,n] = sum_k A[m,k] * B[n,k] ----------------
// BM=BN=128, BK=64. 256 threads = 4 waves (2x2), wave tile 64x64 = 2x2 of
// 32x32x16 MFMA tiles (higher FLOP per LDS byte than 16x16x32).
// 3-deep LDS pipeline, counted vmcnt(16) (T4). XOR swizzle ((row&7)<<4) on
// both global source (LDS dest linear) and ds_read address (T2, rule 21).
// Grid 256 = 1 block/CU; XCD-aware 8x4 chunk swizzle (T1) keeps each XCD's
// A/B panels L2-resident.

#define BM 128
#define BN 128
#define BK 64

__device__ __forceinline__ void gload_lds16(const half_t* g, half_t* l) {
  __builtin_amdgcn_global_load_lds(
      (__attribute__((address_space(1))) uint32_t*)g,
      (__attribute__((address_space(3))) uint32_t*)l, 16, 0, 0);
}

__global__ __launch_bounds__(256, 1) void gemm_kernel(
    const half_t* __restrict__ A, const half_t* __restrict__ B,
    float* __restrict__ C) {
  __shared__ half_t ldsA[3][BM * BK];  // 3 x 16 KB
  __shared__ half_t ldsB[3][BN * BK];  // 3 x 16 KB  (96 KB total)

  const int tid  = threadIdx.x;
  const int lane = tid & 63;
  const int wid  = tid >> 6;
  // XCD swizzle: xcd = bid&7 owns an 8(bm) x 4(bn) chunk of the 16x16 grid
  const int bid = blockIdx.x;
  const int c   = bid & 7;
  const int idx = bid >> 3;               // 0..31
  const int bm  = ((c >> 2) << 3) + (idx >> 2);   // 0..15
  const int bn  = ((c & 3) << 2) + (idx & 3);     // 0..15
  const int wr  = wid >> 1;               // 0..1
  const int wc  = wid & 1;                // 0..1

  const half_t* gA = A + (size_t)(bm * BM) * DIM;
  const half_t* gB = B + (size_t)(bn * BN) * DIM;

  auto stage = [&](half_t* dA, half_t* dB, int kt) {
#pragma unroll
    for (int i = 0; i < 4; ++i) {
      int P   = (i * 256 + tid) * 16;              // byte in 128x64 tile
      int row = P >> 7;
      int cb  = (P & 127) ^ ((row & 7) << 4);
      gload_lds16(gA + (size_t)row * DIM + kt * BK + (cb >> 1),
                  (half_t*)((char*)dA + P));
    }
#pragma unroll
    for (int i = 0; i < 4; ++i) {
      int P   = (i * 256 + tid) * 16;
      int row = P >> 7;
      int cb  = (P & 127) ^ ((row & 7) << 4);
      gload_lds16(gB + (size_t)row * DIM + kt * BK + (cb >> 1),
                  (half_t*)((char*)dB + P));
    }
  };

  f32x16 acc[2][2] = {};

  auto compute = [&](const half_t* cA, const half_t* cB) {
    const int r31 = lane & 31;
    const int swz = (r31 & 7) << 4;                // row&7 == lane&7
#pragma unroll
    for (int ks = 0; ks < 4; ++ks) {
      const int cb = ks * 32 + ((lane >> 5) << 4); // logical col-byte
      const int pc = cb ^ swz;                     // physical col-byte
      f16x8 af[2], bf[2];
#pragma unroll
      for (int mt = 0; mt < 2; ++mt) {
        int row = wr * 64 + mt * 32 + r31;
        af[mt] = *reinterpret_cast<const f16x8*>(
            (const char*)cA + (row << 7) + pc);
      }
#pragma unroll
      for (int nt = 0; nt < 2; ++nt) {
        int row = wc * 64 + nt * 32 + r31;
        bf[nt] = *reinterpret_cast<const f16x8*>(
            (const char*)cB + (row << 7) + pc);
      }
      __builtin_amdgcn_s_setprio(1);
#pragma unroll
      for (int mt = 0; mt < 2; ++mt)
#pragma unroll
        for (int nt = 0; nt < 2; ++nt)
          acc[mt][nt] = __builtin_amdgcn_mfma_f32_32x32x16_f16(
              af[mt], bf[nt], acc[mt][nt], 0, 0, 0);
      __builtin_amdgcn_s_setprio(0);
    }
  };

  half_t* A0 = &ldsA[0][0];  half_t* B0 = &ldsB[0][0];
  half_t* A1 = &ldsA[1][0];  half_t* B1 = &ldsB[1][0];
  half_t* A2 = &ldsA[2][0];  half_t* B2 = &ldsB[2][0];

  stage(A0, B0, 0);
  stage(A1, B1, 1);

  auto iter = [&](int kt, const half_t* cA, const half_t* cB,
                  half_t* sA, half_t* sB) {
    stage(sA, sB, kt + 2);
    asm volatile("s_waitcnt vmcnt(16)" ::: "memory");  // kt's 8 loads done
    __builtin_amdgcn_s_barrier();
    compute(cA, cB);
    __builtin_amdgcn_s_barrier();
  };

  for (int kt = 0; kt < 30; kt += 3) {   // NT=32
    iter(kt + 0, A0, B0, A2, B2);
    iter(kt + 1, A1, B1, A0, B0);
    iter(kt + 2, A2, B2, A1, B1);
  }
  asm volatile("s_waitcnt vmcnt(8)" ::: "memory");
  __builtin_amdgcn_s_barrier();
  compute(A0, B0);
  asm volatile("s_waitcnt vmcnt(0)" ::: "memory");
  __builtin_amdgcn_s_barrier();
  compute(A1, B1);

  // C/D 32x32 layout: col = lane&31, row = (reg&3) + 8*(reg>>2) + 4*(lane>>5)
  const int crow0 = bm * BM + wr * 64 + 4 * (lane >> 5);
  const int ccol0 = bn * BN + wc * 64 + (lane & 31);
#pragma unroll
  for (int mt = 0; mt < 2; ++mt)
#pragma unroll
    for (int nt = 0; nt < 2; ++nt)
#pragma unroll
      for (int r = 0; r < 16; ++r) {
        int row = crow0 + mt * 32 + (r & 3) + 8 * (r >> 2);
        int col = ccol0 + nt * 32;
        C[(size_t)row * DIM + col] = acc[mt][nt][r];
      }
}

// ---------------- launch ----------------

extern "C" void kernel_launch(void* const* d_in, const int* in_sizes, int n_in,
                              void* d_out, int out_size, void* d_ws,
                              size_t ws_size, hipStream_t stream) {
  const float* x = (const float*)d_in[0];
  const float* w = (const float*)d_in[1];
  float* out = (float*)d_out;

  half_t* xq = (half_t*)d_ws;                     // xq ++ wq, 16 MB

  const int ngroups = 2 * TOKENS * DIM / GROUP;   // 65536
  quant2_kernel<<<ngroups / 8, 256, 0, stream>>>(x, w, xq);

  half_t* wq = xq + (size_t)TOKENS * DIM;
  gemm_kernel<<<256, 256, 0, stream>>>(xq, wq, out);
}

// Round 5
// 39.640 us; speedup vs baseline: 2.0367x; 1.0931x over previous
//
#include <hip/hip_runtime.h>
#include <hip/hip_fp16.h>
#include <stdint.h>

#define TOKENS 2048
#define DIM    2048
#define GROUP  128

typedef _Float16 half_t;
typedef __attribute__((ext_vector_type(4)))  _Float16 f16x4;
typedef __attribute__((ext_vector_type(8)))  _Float16 f16x8;
typedef __attribute__((ext_vector_type(4)))  float    f32x4;
typedef __attribute__((ext_vector_type(16))) float    f32x16;

// ---------------- quantization ----------------

__device__ __forceinline__ float group32_sum(float v) {
#pragma unroll
  for (int off = 16; off > 0; off >>= 1)
    v += __shfl_xor(v, off, 64);
  return v;
}

__device__ __forceinline__ float nearest_q(float u) {
  float qi = fminf(fmaxf(rintf(u * 0.25f) * 4.0f, -28.0f), 28.0f);
  float a = fabsf(u);
  float m = a <= 56.f  ? 48.f
          : a <= 80.f  ? 64.f
          : a <= 112.f ? 96.f
          : a <= 160.f ? 128.f
          : a <= 224.f ? 192.f
          : a <= 320.f ? 256.f : 384.f;
  float qo = copysignf(m, u);
  return (fabsf(u - qo) < fabsf(u - qi)) ? qo : qi;
}

__global__ __launch_bounds__(256) void quant2_kernel(
    const float* __restrict__ x, const float* __restrict__ w,
    half_t* __restrict__ out) {
  const int wid  = threadIdx.x >> 6;
  const int lane = threadIdx.x & 63;
  const int l    = lane & 31;
  const int g    = blockIdx.x * 8 + wid * 2 + (lane >> 5);
  const int NG1  = TOKENS * DIM / GROUP;   // 32768

  const float alpha = (g < NG1) ? 0.9f : 1.0f;
  const float* src  = (g < NG1) ? x : w;
  const size_t sbase = (size_t)(g < NG1 ? g : g - NG1) * GROUP + l * 4;

  const float4 v = *reinterpret_cast<const float4*>(src + sbase);

  const float mean = group32_sum(v.x + v.y + v.z + v.w) * (1.0f / 128.0f);
  const float d0 = v.x - mean, d1 = v.y - mean, d2 = v.z - mean, d3 = v.w - mean;
  const float var = group32_sum(d0 * d0 + d1 * d1 + d2 * d2 + d3 * d3) *
                    (1.0f / 127.0f);
  const float scale = (fabsf(mean) + 3.0f * sqrtf(var)) * alpha / 28.0f;
  const float rs = 1.0f / scale;

  float q0 = nearest_q(v.x * rs);
  float q1 = nearest_q(v.y * rs);
  float q2 = nearest_q(v.z * rs);
  float q3 = nearest_q(v.w * rs);
  if (fabsf(q0) > 32.0f)      q1 = 0.0f;
  else if (fabsf(q1) > 32.0f) q0 = 0.0f;
  if (fabsf(q2) > 32.0f)      q3 = 0.0f;
  else if (fabsf(q3) > 32.0f) q2 = 0.0f;

  f16x4 hv;
  hv.x = (half_t)(q0 * scale);
  hv.y = (half_t)(q1 * scale);
  hv.z = (half_t)(q2 * scale);
  hv.w = (half_t)(q3 * scale);
  *reinterpret_cast<f16x4*>(out + (size_t)g * GROUP + l * 4) = hv;
}

// ---------------- GEMM: C[m,n] = sum_k A[m,k] * B[n,k] ----------------
// BM=BN=128, BK=64. 512 threads = 8 waves = 2 waves/SIMD (latency hiding).
// Wave (wr,wc,wz): output tile 64x64 at (wr,wc), K-half wz (ks = 2*wz..2*wz+1)
// -> ratio 1.0 LDS-reads/MFMA kept while doubling occupancy. Epilogue:
// wz=1 waves dump acc into the (dead) pipeline LDS, wz=0 waves add + store.
// 3-deep pipeline, counted vmcnt (T4); XOR swizzle ((row&7)<<4) both-sides
// (T2, rule 21); XCD-aware 8x4 chunk swizzle (T1).

#define BM 128
#define BN 128
#define BK 64

__device__ __forceinline__ void gload_lds16(const half_t* g, half_t* l) {
  __builtin_amdgcn_global_load_lds(
      (__attribute__((address_space(1))) uint32_t*)g,
      (__attribute__((address_space(3))) uint32_t*)l, 16, 0, 0);
}

__global__ __launch_bounds__(512, 1) void gemm_kernel(
    const half_t* __restrict__ A, const half_t* __restrict__ B,
    float* __restrict__ C) {
  __shared__ char lds_raw[3 * 32768];   // 96 KB: 3 stages x (A 16K + B 16K)

  const int tid  = threadIdx.x;
  const int lane = tid & 63;
  const int wid  = tid >> 6;           // 0..7
  const int wz   = wid & 1;            // K-half
  const int wq   = wid >> 1;           // 0..3
  const int wr   = wq >> 1;            // 0..1
  const int wc   = wq & 1;             // 0..1

  const int bid = blockIdx.x;
  const int c   = bid & 7;
  const int idx = bid >> 3;
  const int bm  = ((c >> 2) << 3) + (idx >> 2);
  const int bn  = ((c & 3) << 2) + (idx & 3);

  const half_t* gA = A + (size_t)(bm * BM) * DIM;
  const half_t* gB = B + (size_t)(bn * BN) * DIM;

  auto stage = [&](char* buf, int kt) {
#pragma unroll
    for (int i = 0; i < 2; ++i) {      // A: 16384 B / (512 thr * 16 B) = 2
      int P   = (i * 512 + tid) * 16;
      int row = P >> 7;
      int cb  = (P & 127) ^ ((row & 7) << 4);
      gload_lds16(gA + (size_t)row * DIM + kt * BK + (cb >> 1),
                  (half_t*)(buf + P));
    }
#pragma unroll
    for (int i = 0; i < 2; ++i) {      // B
      int P   = (i * 512 + tid) * 16;
      int row = P >> 7;
      int cb  = (P & 127) ^ ((row & 7) << 4);
      gload_lds16(gB + (size_t)row * DIM + kt * BK + (cb >> 1),
                  (half_t*)(buf + 16384 + P));
    }
  };

  f32x16 acc[2][2] = {};

  auto compute = [&](const char* buf) {
    const char* cA = buf;
    const char* cB = buf + 16384;
    const int r31 = lane & 31;
    const int swz = (r31 & 7) << 4;
#pragma unroll
    for (int ksi = 0; ksi < 2; ++ksi) {
      const int ks = wz * 2 + ksi;                 // this wave's K-half
      const int cb = ks * 32 + ((lane >> 5) << 4);
      const int pc = cb ^ swz;
      f16x8 af[2], bf[2];
#pragma unroll
      for (int mt = 0; mt < 2; ++mt) {
        int row = wr * 64 + mt * 32 + r31;
        af[mt] = *reinterpret_cast<const f16x8*>(cA + (row << 7) + pc);
      }
#pragma unroll
      for (int nt = 0; nt < 2; ++nt) {
        int row = wc * 64 + nt * 32 + r31;
        bf[nt] = *reinterpret_cast<const f16x8*>(cB + (row << 7) + pc);
      }
      __builtin_amdgcn_s_setprio(1);
#pragma unroll
      for (int mt = 0; mt < 2; ++mt)
#pragma unroll
        for (int nt = 0; nt < 2; ++nt)
          acc[mt][nt] = __builtin_amdgcn_mfma_f32_32x32x16_f16(
              af[mt], bf[nt], acc[mt][nt], 0, 0, 0);
      __builtin_amdgcn_s_setprio(0);
    }
  };

  char* S0 = lds_raw;
  char* S1 = lds_raw + 32768;
  char* S2 = lds_raw + 65536;

  stage(S0, 0);
  stage(S1, 1);

  auto iter = [&](int kt, const char* cbuf, char* sbuf) {
    stage(sbuf, kt + 2);
    asm volatile("s_waitcnt vmcnt(8)" ::: "memory");  // oldest stage done
    __builtin_amdgcn_s_barrier();
    compute(cbuf);
    __builtin_amdgcn_s_barrier();
  };

  for (int kt = 0; kt < 30; kt += 3) {   // NT = 32
    iter(kt + 0, S0, S2);
    iter(kt + 1, S1, S0);
    iter(kt + 2, S2, S1);
  }
  asm volatile("s_waitcnt vmcnt(4)" ::: "memory");
  __builtin_amdgcn_s_barrier();
  compute(S0);                            // kt = 30
  asm volatile("s_waitcnt vmcnt(0)" ::: "memory");
  __builtin_amdgcn_s_barrier();
  compute(S1);                            // kt = 31

  // ---- cross-wave K reduction: wz=1 -> LDS, wz=0 adds + stores ----
  __syncthreads();                        // pipeline LDS now dead
  float* red = (float*)lds_raw;           // 64 KB used
  if (wz == 1) {
#pragma unroll
    for (int mt = 0; mt < 2; ++mt)
#pragma unroll
      for (int nt = 0; nt < 2; ++nt) {
        const int t = mt * 2 + nt;
#pragma unroll
        for (int q = 0; q < 4; ++q) {
          f32x4 v;
          v.x = acc[mt][nt][q * 4 + 0];
          v.y = acc[mt][nt][q * 4 + 1];
          v.z = acc[mt][nt][q * 4 + 2];
          v.w = acc[mt][nt][q * 4 + 3];
          *reinterpret_cast<f32x4*>(
              red + (size_t)((wq * 16 + t * 4 + q) * 64 + lane) * 4) = v;
        }
      }
  }
  __syncthreads();
  if (wz == 0) {
    const int crow0 = bm * BM + wr * 64 + 4 * (lane >> 5);
    const int ccol0 = bn * BN + wc * 64 + (lane & 31);
#pragma unroll
    for (int mt = 0; mt < 2; ++mt)
#pragma unroll
      for (int nt = 0; nt < 2; ++nt) {
        const int t = mt * 2 + nt;
#pragma unroll
        for (int q = 0; q < 4; ++q) {
          f32x4 v = *reinterpret_cast<const f32x4*>(
              red + (size_t)((wq * 16 + t * 4 + q) * 64 + lane) * 4);
          acc[mt][nt][q * 4 + 0] += v.x;
          acc[mt][nt][q * 4 + 1] += v.y;
          acc[mt][nt][q * 4 + 2] += v.z;
          acc[mt][nt][q * 4 + 3] += v.w;
        }
#pragma unroll
        for (int r = 0; r < 16; ++r) {
          int row = crow0 + mt * 32 + (r & 3) + 8 * (r >> 2);
          int col = ccol0 + nt * 32;
          C[(size_t)row * DIM + col] = acc[mt][nt][r];
        }
      }
  }
}

// ---------------- launch ----------------

extern "C" void kernel_launch(void* const* d_in, const int* in_sizes, int n_in,
                              void* d_out, int out_size, void* d_ws,
                              size_t ws_size, hipStream_t stream) {
  const float* x = (const float*)d_in[0];
  const float* w = (const float*)d_in[1];
  float* out = (float*)d_out;

  half_t* xq = (half_t*)d_ws;                     // xq ++ wq, 16 MB

  const int ngroups = 2 * TOKENS * DIM / GROUP;   // 65536
  quant2_kernel<<<ngroups / 8, 256, 0, stream>>>(x, w, xq);

  half_t* wq = xq + (size_t)TOKENS * DIM;
  gemm_kernel<<<256, 512, 0, stream>>>(xq, wq, out);
}